// Round 5
// 6278.873 us; speedup vs baseline: 1.0071x; 1.0071x over previous
//
#include <hip/hip_runtime.h>
#include <cstdint>
#include <cmath>

// Problem constants
#define V_SZ 5000
#define H_SZ 512
#define N_SZ 8
#define T_LEN 2048
#define NTV (81920000LL)   // N*T*V

typedef __bf16 bf16;
typedef __bf16 bf16x2 __attribute__((ext_vector_type(2)));
typedef __bf16 bf16x8 __attribute__((ext_vector_type(8)));
typedef float  f32x4  __attribute__((ext_vector_type(4)));
typedef int    i32x4  __attribute__((ext_vector_type(4)));

// ---------------------------------------------------------------------------
// LLC-coherent 16B accesses (bypass L1+L2 via sc0 sc1). A chunk is
// [data0, tag, data1, tag] so an 8B split cannot tear data from its tag.
// (Harness-verified exchange protocol — unchanged from the 6323us baseline.)
// ---------------------------------------------------------------------------
__device__ __forceinline__ void llc_store16(void* p, i32x4 v) {
    asm volatile("global_store_dwordx4 %0, %1, off sc0 sc1"
                 :: "v"(p), "v"(v) : "memory");
}
__device__ __forceinline__ void llc_load2(const void* p0, const void* p1,
                                          i32x4& a, i32x4& b) {
    asm volatile("global_load_dwordx4 %0, %2, off sc0 sc1\n\t"
                 "global_load_dwordx4 %1, %3, off sc0 sc1\n\t"
                 "s_waitcnt vmcnt(0)"
                 : "=&v"(a), "=&v"(b)
                 : "v"(p0), "v"(p1)
                 : "memory");
}

// ---------------------------------------------------------------------------
// Kernel 1: convert Wo (fp32 [5000][512]) -> bf16 padded [5120][512]
// ---------------------------------------------------------------------------
__global__ __launch_bounds__(256) void prep_wo(const float* __restrict__ Wo,
                                               bf16* __restrict__ Wo16) {
    int idx = (blockIdx.x * 256 + threadIdx.x) * 4;
    if (idx >= 5120 * 512) return;
    float4 v = make_float4(0.f, 0.f, 0.f, 0.f);
    if (idx < V_SZ * H_SZ) v = *(const float4*)(Wo + idx);
    Wo16[idx + 0] = (bf16)v.x;
    Wo16[idx + 1] = (bf16)v.y;
    Wo16[idx + 2] = (bf16)v.z;
    Wo16[idx + 3] = (bf16)v.w;
}

// ---------------------------------------------------------------------------
// Kernel 2: recurrence, 4 blocks x 1024 threads (VERIFIED baseline protocol:
// blockIdx = worker id, LLC exchange, global spin budget). Three intra-block
// latency edits vs baseline:
//  (a) register publish: after tanh, thread pairs swap h via shfl_xor(1);
//      even tid stores its 16B chunk immediately -> barrier 3 + hnewL gone
//      (2 barriers/step). Chunk format/address identical to baseline.
//  (b) per-thread token load + E-gather issued BEFORE the spin loop: E
//      latency fully hidden under the exchange spin (tokL LDS gone).
//  (c) MFMA accumulator split into 2 independent chains (dep latency /2).
// ---------------------------------------------------------------------------
__global__ __launch_bounds__(1024, 1) void rnn_rec3(
        const int*   __restrict__ x,
        const float* __restrict__ E,
        const float* __restrict__ Wh,
        const float* __restrict__ bh,
        char*        __restrict__ Hx,
        bf16*        __restrict__ Hall,
        float*       __restrict__ out) {
    __shared__ bf16  Abuf[2 * 16 * 520];    // 33.3 KB, double-buffered A
    __shared__ float Ds[16 * 272];          // 17.4 KB, D per wave, stride 17

    const int tid  = threadIdx.x;
    const int blk  = blockIdx.x;            // 0..3
    const int lane = tid & 63;
    const int wv   = tid >> 6;              // 0..15
    const int l15  = lane & 15;
    const int quad = lane >> 4;
    const int j0   = blk * 128;

    // zero both A buffers (h0 = 0)
    for (int i = tid; i < 2 * 16 * 520; i += 1024) Abuf[i] = (bf16)0.f;

    // W fragments -> registers. Wave w<8: W_hi of j-tile w; w>=8: W_lo of w-8.
    bf16x8 wf[16];
    {
        const float* wrow = Wh + (size_t)(j0 + (wv & 7) * 16 + l15) * H_SZ;
        const bool lo_pass = (wv >= 8);
#pragma unroll
        for (int kt = 0; kt < 16; ++kt) {
            const float* p = wrow + kt * 32 + quad * 8;
            bf16x8 f;
#pragma unroll
            for (int i = 0; i < 8; ++i) {
                float v = p[i];
                bf16 hi = (bf16)v;
                f[i] = lo_pass ? (bf16)(v - (float)hi) : hi;
            }
            wf[kt] = f;
        }
    }

    const int rn = tid >> 7, rj = tid & 127;   // reducer output (batch, local j)
    const float bhv = bh[j0 + rj];
    const int jt = rj >> 4, jl = rj & 15;
    const int* xrow = x + rn * T_LEN;          // this thread's token stream

    // reader chunk precompute: 3 remote blocks x 512 chunks = 1536
    int off0, off1, dst0, dst1;
    bool has1 = (tid < 512);
    {
        int c0 = tid;
        int rbp0 = c0 >> 9, cc0 = c0 & 511;
        int rb0 = rbp0 + (rbp0 >= blk);
        off0 = (rb0 * 512 + cc0) * 16;
        dst0 = (cc0 >> 6) * 520 + rb0 * 128 + 2 * (cc0 & 63);
        int c1 = has1 ? (tid + 1024) : c0;
        int rbp1 = c1 >> 9, cc1 = c1 & 511;
        int rb1 = rbp1 + (rbp1 >= blk);
        off1 = (rb1 * 512 + cc1) * 16;
        dst1 = (cc1 >> 6) * 520 + rb1 * 128 + 2 * (cc1 & 63);
    }

    int budget = 1 << 22;
    __syncthreads();

    for (int t = 0; t < T_LEN; ++t) {
        // (b) token + embedding gather issued BEFORE the spin: hidden under it
        const float ev = E[(size_t)xrow[t] * H_SZ + j0 + rj];

        // P1: gather remote slices of h_t into A[t&1]
        if (t > 0) {
            const char* base = Hx + (size_t)(t & 1) * 32768;
            bf16* An = Abuf + (t & 1) * (16 * 520);
            const int wtag = t;
            const void* p0 = base + off0;
            const void* p1 = base + off1;
            bool need0 = true, need1 = has1;
            while (need0 | need1) {
                i32x4 a, b;
                llc_load2(p0, p1, a, b);
                if (need0 & (a.y == wtag) & (a.w == wtag)) {
                    float h0 = __int_as_float(a.x), h1 = __int_as_float(a.z);
                    bf16 hi0 = (bf16)h0, hi1 = (bf16)h1;
                    *(bf16x2*)(An + dst0) = (bf16x2){hi0, hi1};
                    *(bf16x2*)(An + 8 * 520 + dst0) =
                        (bf16x2){(bf16)(h0 - (float)hi0), (bf16)(h1 - (float)hi1)};
                    need0 = false;
                }
                if (need1 & (b.y == wtag) & (b.w == wtag)) {
                    float h0 = __int_as_float(b.x), h1 = __int_as_float(b.z);
                    bf16 hi0 = (bf16)h0, hi1 = (bf16)h1;
                    *(bf16x2*)(An + dst1) = (bf16x2){hi0, hi1};
                    *(bf16x2*)(An + 8 * 520 + dst1) =
                        (bf16x2){(bf16)(h0 - (float)hi0), (bf16)(h1 - (float)hi1)};
                    need1 = false;
                }
                if (--budget < 0) break;
            }
        }
        __syncthreads();   // [B1] A(t) ready; orders Ds(t-1) reads vs Ds(t) writes

        // P3: MFMA  D[m][j] = A[m][k] * W[j][k]  (two independent chains)
        {
            const bf16* Ab = Abuf + (t & 1) * (16 * 520);
            f32x4 acc = {}, acc2 = {};
#pragma unroll
            for (int kt = 0; kt < 16; kt += 2) {
                bf16x8 af0 = *(const bf16x8*)(Ab + l15 * 520 + kt * 32 + quad * 8);
                bf16x8 af1 = *(const bf16x8*)(Ab + l15 * 520 + (kt + 1) * 32 + quad * 8);
                acc  = __builtin_amdgcn_mfma_f32_16x16x32_bf16(af0, wf[kt],     acc,  0, 0, 0);
                acc2 = __builtin_amdgcn_mfma_f32_16x16x32_bf16(af1, wf[kt + 1], acc2, 0, 0, 0);
            }
            acc += acc2;
#pragma unroll
            for (int r = 0; r < 4; ++r)
                Ds[wv * 272 + (quad * 4 + r) * 17 + l15] = acc[r];
        }
        __syncthreads();   // [B2] Ds(t) ready

        // P4: reduce 4 quadrants + tanh; publish straight from registers
        {
            float s = Ds[jt * 272 + rn * 17 + jl]
                    + Ds[jt * 272 + (rn + 8) * 17 + jl]
                    + Ds[(jt + 8) * 272 + rn * 17 + jl]
                    + Ds[(jt + 8) * 272 + (rn + 8) * 17 + jl];
            float h = tanhf(s + bhv + ev);

            // (a) publish FIRST, from registers (this is what remote blocks
            // wait on). Pair (even tid, odd tid) = cols (2jp, 2jp+1), same rn.
            float hodd = __shfl_xor(h, 1, 64);
            if (((tid & 1) == 0) & (t < T_LEN - 1)) {
                i32x4 ch;
                ch.x = __float_as_int(h);
                ch.y = t + 1;
                ch.z = __float_as_int(hodd);
                ch.w = t + 1;
                char* dstp = Hx + (size_t)((t + 1) & 1) * 32768
                           + (size_t)(blk * 512 + rn * 64 + (rj >> 1)) * 16;
                llc_store16(dstp, ch);
            }

            // own An staging for next step + Hall for the output GEMM
            Hall[((size_t)rn * T_LEN + t) * H_SZ + j0 + rj] = (bf16)h;
            bf16 hi = (bf16)h;
            bf16* An = Abuf + ((t + 1) & 1) * (16 * 520);
            An[rn * 520 + j0 + rj] = hi;
            An[(rn + 8) * 520 + j0 + rj] = (bf16)(h - (float)hi);
            if (t == T_LEN - 1) out[NTV + rn * H_SZ + j0 + rj] = h;
        }
        // no third barrier: next B1 orders P4's An(t+1)/Ds reads against the
        // next iteration's writes; An(t+1) own/remote writer regions disjoint.
    }
}

// ---------------------------------------------------------------------------
// Kernel 3: Z = Hall(16384x512 bf16) * Wo16^T(5120x512 bf16) + bo, fp32 out.
// ---------------------------------------------------------------------------
#define LDK 72
__global__ __launch_bounds__(256) void gemm_bt(
        const bf16* __restrict__ A,
        const bf16* __restrict__ B,
        const float* __restrict__ bo,
        float* __restrict__ C) {
    __shared__ bf16 As[128 * LDK];
    __shared__ bf16 Bs[128 * LDK];

    const int tid  = threadIdx.x;
    const int lane = tid & 63;
    const int wid  = tid >> 6;
    const int wm   = wid & 1, wn = wid >> 1;
    const int bm   = blockIdx.y, bn = blockIdx.x;
    const int rowA0 = bm * 128, rowB0 = bn * 128;

    const int quad = lane >> 4;
    const int l15  = lane & 15;

    f32x4 acc[4][4] = {};

    for (int kt = 0; kt < H_SZ / 64; ++kt) {
        __syncthreads();
#pragma unroll
        for (int i = 0; i < 4; ++i) {
            int p = i * 256 + tid;
            int r = p >> 3, c8 = p & 7;
            bf16x8 va = *(const bf16x8*)(A + (size_t)(rowA0 + r) * H_SZ + kt * 64 + c8 * 8);
            *(bf16x8*)(As + r * LDK + c8 * 8) = va;
            bf16x8 vb = *(const bf16x8*)(B + (size_t)(rowB0 + r) * H_SZ + kt * 64 + c8 * 8);
            *(bf16x8*)(Bs + r * LDK + c8 * 8) = vb;
        }
        __syncthreads();

#pragma unroll
        for (int ks = 0; ks < 2; ++ks) {
            bf16x8 af[4], bfr[4];
            const int koff = ks * 32 + quad * 8;
#pragma unroll
            for (int mi = 0; mi < 4; ++mi) {
                int row = wm * 64 + mi * 16 + l15;
                af[mi] = *(const bf16x8*)(As + row * LDK + koff);
            }
#pragma unroll
            for (int ni = 0; ni < 4; ++ni) {
                int row = wn * 64 + ni * 16 + l15;
                bfr[ni] = *(const bf16x8*)(Bs + row * LDK + koff);
            }
#pragma unroll
            for (int mi = 0; mi < 4; ++mi)
#pragma unroll
                for (int ni = 0; ni < 4; ++ni)
                    acc[mi][ni] = __builtin_amdgcn_mfma_f32_16x16x32_bf16(
                        af[mi], bfr[ni], acc[mi][ni], 0, 0, 0);
        }
    }

#pragma unroll
    for (int mi = 0; mi < 4; ++mi) {
#pragma unroll
        for (int ni = 0; ni < 4; ++ni) {
            int vcol = rowB0 + wn * 64 + ni * 16 + l15;
            if (vcol >= V_SZ) continue;
            float bias = bo[vcol];
#pragma unroll
            for (int r = 0; r < 4; ++r) {
                int m = rowA0 + wm * 64 + mi * 16 + quad * 4 + r;
                C[(size_t)m * V_SZ + vcol] = acc[mi][ni][r] + bias;
            }
        }
    }
}

// ---------------------------------------------------------------------------
// Kernel 4: in-place row softmax over V=5000. One block per row.
// ---------------------------------------------------------------------------
__global__ __launch_bounds__(256) void softmax_rows(float* __restrict__ z) {
    __shared__ float buf[5008];
    __shared__ float red[8];
    const int tid = threadIdx.x;
    const int lane = tid & 63;
    const int wid = tid >> 6;
    const size_t base = (size_t)blockIdx.x * V_SZ;

    float lm = -3.4e38f;
    for (int i = tid; i < V_SZ; i += 256) {
        float v = z[base + i];
        buf[i] = v;
        lm = fmaxf(lm, v);
    }
#pragma unroll
    for (int o = 32; o; o >>= 1) lm = fmaxf(lm, __shfl_down(lm, o, 64));
    if (lane == 0) red[wid] = lm;
    __syncthreads();
    const float m = fmaxf(fmaxf(red[0], red[1]), fmaxf(red[2], red[3]));

    float ls = 0.f;
    for (int i = tid; i < V_SZ; i += 256) {
        float e = __expf(buf[i] - m);
        buf[i] = e;
        ls += e;
    }
#pragma unroll
    for (int o = 32; o; o >>= 1) ls += __shfl_down(ls, o, 64);
    __syncthreads();
    if (lane == 0) red[4 + wid] = ls;
    __syncthreads();
    const float inv = 1.0f / (red[4] + red[5] + red[6] + red[7]);
    for (int i = tid; i < V_SZ; i += 256) z[base + i] = buf[i] * inv;
}

// ---------------------------------------------------------------------------
// Workspace layout (bytes):
//   [0, 65536)      Hx tagged exchange (2 parity x 4 blk x 512 chunks x 16B)
//   [65536, ...)    Wo16 bf16 [5120*512]
//   [8388608, ...)  Hall bf16 [16384*512]
// No memset needed: tags are exact-match; A-LDS zeroed in-kernel.
// ---------------------------------------------------------------------------
extern "C" void kernel_launch(void* const* d_in, const int* in_sizes, int n_in,
                              void* d_out, int out_size, void* d_ws, size_t ws_size,
                              hipStream_t stream) {
    const int*   x  = (const int*)d_in[0];
    const float* E  = (const float*)d_in[1];
    const float* Wh = (const float*)d_in[2];
    const float* bh = (const float*)d_in[3];
    const float* Wo = (const float*)d_in[4];
    const float* bo = (const float*)d_in[5];
    float* out = (float*)d_out;

    char* ws = (char*)d_ws;
    char*  Hx   = ws;
    bf16*  Wo16 = (bf16*)(ws + 65536);
    bf16*  Hall = (bf16*)(ws + 8388608);

    prep_wo<<<2560, 256, 0, stream>>>(Wo, Wo16);
    rnn_rec3<<<4, 1024, 0, stream>>>(x, E, Wh, bh, Hx, Hall, out);
    gemm_bt<<<dim3(40, 128), 256, 0, stream>>>(Hall, Wo16, bo, out);
    softmax_rows<<<16384, 256, 0, stream>>>(out);
}